// Round 5
// baseline (432.336 us; speedup 1.0000x reference)
//
#include <hip/hip_runtime.h>
#include <hip/hip_bf16.h>

#define HH 192
#define WW 192
#define HW 36864           // 192*192
#define CHW 2359296        // 64*36864

typedef __attribute__((ext_vector_type(8))) short short8;
typedef __attribute__((ext_vector_type(4))) float float4v;

static __device__ __forceinline__ unsigned short f2bu(float f) {
  union { float f; unsigned u; } v; v.f = f;
  unsigned r = (v.u + 0x7fffu + ((v.u >> 16) & 1u)) >> 16;   // RNE bf16
  return (unsigned short)r;
}

static __device__ __forceinline__ float bu2f(unsigned short s) {
  union { unsigned u; float f; } v; v.u = ((unsigned)s) << 16;
  return v.f;
}

// ---------------------------------------------------------------- prep ----
// wB1/wB2 repack, wfuse transpose, tmp zero. (u zeroing removed: new k_pnp
// writes u0 with direct stores, full coverage.)  360448 = 1408*256 elems.
__global__ void k_prep(const float* __restrict__ c1w, const float* __restrict__ c2w,
                       const float* __restrict__ wfuse,
                       unsigned short* __restrict__ wB1, unsigned short* __restrict__ wB2,
                       float* __restrict__ wfT, float* __restrict__ tmp) {
  int i = blockIdx.x * 256 + threadIdx.x;
  if (i < 147456) {
    int T = i / 9216, r = i % 9216;
    int s = r / 512, e = r % 512;
    int l = e >> 3, j = e & 7;
    int m = l & 15, q = l >> 4;
    int oc = T * 16 + m;
    int k = s * 32 + q * 8 + j;
    int tap = k >> 6, ic = k & 63;
    int ky = tap / 3, kx = tap % 3;
    wB1[i] = f2bu(c1w[((oc * 64 + ic) * 3 + ky) * 3 + kx]);
    return;
  }
  int j2 = i - 147456;
  if (j2 < 16384) {
    int g = j2 / 512, e = j2 % 512;
    int l = e >> 3, jj = e & 7;
    int m = l & 15, q = l >> 4;
    int w = g / 8, s2 = g % 8;
    wB2[j2] = f2bu(c2w[(w * 16 + m) * 256 + s2 * 32 + q * 8 + jj]);
    return;
  }
  int k3 = j2 - 16384;
  if (k3 < 131072) { int jj = k3 >> 8, r = k3 & 255; wfT[k3] = wfuse[r * 512 + jj]; return; }
  int z = k3 - 131072;
  if (z < 65536) tmp[z] = 0.f;
}

// ---------------------------------------------------- init polys + out0 ----
__global__ void k_init_polys(const float* __restrict__ wh, const int* __restrict__ ct_ind,
                             const int* __restrict__ ct_img,
                             float* __restrict__ initp, float* __restrict__ out0) {
  int n = blockIdx.x;     // 0..127
  int p = threadIdx.x;    // 0..127
  int ind = ct_ind[n], img = ct_img[n];
  int cx = ind % WW, cy = ind / WW;
  size_t base = ((size_t)(img * 256 + 2 * p)) * HW + (size_t)cy * WW + cx;
  float ox = wh[base];
  float oy = wh[base + HW];
  float px = __fadd_rn(__fmul_rn(ox, 10.0f), (float)cx);
  float py = __fadd_rn(__fmul_rn(oy, 10.0f), (float)cy);
  initp[n * 256 + 2 * p]     = px;
  initp[n * 256 + 2 * p + 1] = py;
  out0[n * 256 + 2 * p]      = __fmul_rn(px, 4.0f);
  out0[n * 256 + 2 * p + 1]  = __fmul_rn(py, 4.0f);
}

// ------------------------------------------------------ point-in-polygon ----
// v2: block = (row, batch). 32 polys per block (batch 0: polys 0..31, else
// 32..63 — replicates reference _mask_batch slicing bug). Per-poly crossing
// lists + masks staged in LDS; union row direct-stored (no atomics, no
// zero-fill). If fgate != null, the block also applies the union gate to
// feat[b][:,row,:] in place (fused k_final).
__global__ __launch_bounds__(256) void k_pnp(const float* __restrict__ polys,
    float* __restrict__ outm, float* __restrict__ uout, float* __restrict__ fgate) {
  int row = blockIdx.x;       // 0..191
  int b   = blockIdx.y;       // 0..3
  int t = threadIdx.x;
  int w = t >> 6, lane = t & 63;
  __shared__ float xint[32][128];
  __shared__ int   cnt[32];
  __shared__ float mrow[32][192];
  __shared__ float urow[192];
  if (t < 32) cnt[t] = 0;
  __syncthreads();
  int nbase = (b == 0) ? 0 : 32;
  float yy = (float)row;
  // phase 1: each wave handles 8 polys; 64 lanes x 2 edges each
  for (int pc = 0; pc < 8; ++pc) {
    int c = w * 8 + pc;
    const float* P = polys + (nbase + c) * 256;
    for (int e = lane; e < 128; e += 64) {
      float y1 = P[2 * e + 1], y2 = P[2 * ((e + 1) & 127) + 1];
      if ((y1 > yy) != (y2 > yy)) {
        float x1 = P[2 * e], x2 = P[2 * ((e + 1) & 127)];
        float den = __fsub_rn(y2, y1);
        if (fabsf(den) < 1e-9f) den = 1e-9f;
        float xi = __fadd_rn(x1, __fdiv_rn(__fmul_rn(__fsub_rn(x2, x1), __fsub_rn(yy, y1)), den));
        xint[c][atomicAdd(&cnt[c], 1)] = xi;
      }
    }
  }
  __syncthreads();
  // phase 2: (poly c, pixel xp) pairs -> mask; write mb + stage for union
  for (int idx = t; idx < 32 * 192; idx += 256) {
    int c = idx / 192, xp = idx - c * 192;
    float xf = (float)xp;
    int mm = cnt[c], cr = 0;
    for (int j = 0; j < mm; ++j) cr += (xf < xint[c][j]) ? 1 : 0;
    float mv = (float)(cr & 1);
    mrow[c][xp] = mv;
    outm[((size_t)(b * 32 + c) * HH + row) * WW + xp] = mv;
  }
  __syncthreads();
  // phase 3: union over polys
  if (t < 192) {
    float u = 0.f;
#pragma unroll
    for (int c = 0; c < 32; ++c) u = fmaxf(u, mrow[c][t]);
    urow[t] = u;
    if (uout) uout[(size_t)b * HW + (size_t)row * WW + t] = u;
  }
  __syncthreads();
  // phase 4 (optional): fused final gate, feat[b][:,row,:] RW in place
  if (fgate) {
    float* fb = fgate + (size_t)b * CHW + (size_t)row * WW;
    for (int idx = t; idx < 64 * 48; idx += 256) {
      int chn = idx / 48, qx = idx - chn * 48;
      float4v f = *(float4v*)&fb[(size_t)chn * HW + qx * 4];
      float4v o;
#pragma unroll
      for (int j = 0; j < 4; ++j) {
        float uu = urow[qx * 4 + j];
        o[j] = fmaxf(__fadd_rn(__fmul_rn(uu, f[j]), f[j]), 0.f);
      }
      *(float4v*)&fb[(size_t)chn * HW + qx * 4] = o;
    }
  }
}

// ------------------------------------------- fused conv1+relu+conv2+gate ----
// v4 (unchanged from round 4): M=64 px tile, N=256 oc, 4 waves, 3 blocks/CU.
__global__ __launch_bounds__(256, 3) void k_conv(const float* __restrict__ x,
    const unsigned short* __restrict__ wB1, const float* __restrict__ b1,
    const unsigned short* __restrict__ wB2, const float* __restrict__ b2,
    const float* __restrict__ u0, float* __restrict__ feat,
    unsigned short* __restrict__ featT) {
  int blk = blockIdx.x;            // 4 * 96 * 6 = 2304
  int b    = blk / 576;
  int rem  = blk % 576;
  int pair = rem / 6;
  int xs   = rem % 6;
  int y0 = pair * 2, x0 = xs * 32;
  int t = threadIdx.x;
  int w = t >> 6, l = t & 63;
  int m = l & 15, q = l >> 4;

  __shared__ __align__(16) unsigned short sb[16896];   // 33.8 KB union buffer

  // ---- stage x halo: 4 rows x 34 px x 64 ic -> bf16 [(r*34+xx)*72 + ic]
  {
    int kq = t & 7;
    int pr = t >> 3;
    for (int itr = 0; itr < 8; ++itr) {
      int pi = itr * 32 + pr;
      int r  = pi >> 6;
      int ic = pi & 63;
      int gy = y0 + r - 1;
      float4v v = (float4v){0.f, 0.f, 0.f, 0.f};
      if (gy >= 0 && gy < HH)
        v = *(const float4v*)&x[(size_t)(b * 64 + ic) * HW + (size_t)gy * WW + x0 + kq * 4];
      int base = (r * 34 + 1 + kq * 4) * 72 + ic;
      sb[base]       = f2bu(v[0]);
      sb[base + 72]  = f2bu(v[1]);
      sb[base + 144] = f2bu(v[2]);
      sb[base + 216] = f2bu(v[3]);
    }
    for (int itr = 0; itr < 2; ++itr) {
      int e = itr * 256 + t;
      int xxh = e >> 8;
      int rm = e & 255;
      int r = rm >> 6, ic = rm & 63;
      int gy = y0 + r - 1;
      int gx = x0 - 1 + xxh * 33;
      float v = 0.f;
      if (gy >= 0 && gy < HH && gx >= 0 && gx < WW)
        v = x[(size_t)(b * 64 + ic) * HW + (size_t)gy * WW + gx];
      sb[(r * 34 + xxh * 33) * 72 + ic] = f2bu(v);
    }
  }
  __syncthreads();

  // ---- conv1: M=64, N=64 (this wave), K=576
  float4v acc1[4][4];
#pragma unroll
  for (int nt = 0; nt < 4; ++nt) {
    float bv = b1[w * 64 + nt * 16 + m];
#pragma unroll
    for (int mt = 0; mt < 4; ++mt) acc1[mt][nt] = (float4v){bv, bv, bv, bv};
  }

#pragma unroll
  for (int s = 0; s < 18; ++s) {
    int tap = s >> 1, ky = tap / 3, kx = tap - ky * 3;
    int ic0 = (s & 1) * 32 + q * 8;
    short8 bF[4];
#pragma unroll
    for (int nt = 0; nt < 4; ++nt)
      bF[nt] = *(const short8*)&wB1[(size_t)((((w * 4 + nt) * 18 + s) * 512) + l * 8)];
    short8 aF[4];
#pragma unroll
    for (int mt = 0; mt < 4; ++mt) {
      int col  = (mt & 1) * 16 + m + kx;
      int rowi = ky + (mt >> 1);
      aF[mt] = *(const short8*)&sb[(rowi * 34 + col) * 72 + ic0];
    }
#pragma unroll
    for (int nt = 0; nt < 4; ++nt)
#pragma unroll
      for (int mt = 0; mt < 4; ++mt)
        acc1[mt][nt] = __builtin_amdgcn_mfma_f32_16x16x32_bf16(aF[mt], bF[nt], acc1[mt][nt], 0, 0, 0);
  }
  __syncthreads();

  // ---- y1 (relu, bf16) -> LDS [p*264 + oc], p = 0..63
#pragma unroll
  for (int mt = 0; mt < 4; ++mt)
#pragma unroll
    for (int nt = 0; nt < 4; ++nt)
#pragma unroll
      for (int r = 0; r < 4; ++r) {
        int p = mt * 16 + q * 4 + r;
        int oc = w * 64 + nt * 16 + m;
        sb[p * 264 + oc] = f2bu(fmaxf(acc1[mt][nt][r], 0.f));
      }
  __syncthreads();

  // ---- conv2: M=64, N=16 (this wave), K=256
  float4v acc2[4];
  {
    float bv = b2[w * 16 + m];
#pragma unroll
    for (int mt = 0; mt < 4; ++mt) acc2[mt] = (float4v){bv, bv, bv, bv};
  }
#pragma unroll
  for (int s2 = 0; s2 < 8; ++s2) {
    short8 bF2 = *(const short8*)&wB2[(size_t)(((w * 8 + s2) * 512) + l * 8)];
#pragma unroll
    for (int mt = 0; mt < 4; ++mt) {
      short8 a2 = *(const short8*)&sb[(mt * 16 + m) * 264 + s2 * 32 + q * 8];
      acc2[mt] = __builtin_amdgcn_mfma_f32_16x16x32_bf16(a2, bF2, acc2[mt], 0, 0, 0);
    }
  }
  __syncthreads();

  // ---- epilogue: transpose via LDS (wave-private, 16c x 64px pad 68)
  float* fS = (float*)sb;
#pragma unroll
  for (int mt = 0; mt < 4; ++mt)
#pragma unroll
    for (int r = 0; r < 4; ++r) {
      int p = mt * 16 + q * 4 + r;
      fS[w * 1088 + m * 68 + p] = acc2[mt][r];
    }
  const float* ub = u0 + b * HW;
  {
    int gy = y0 + (l >> 5), gx = x0 + (l & 31);
    float uu = ub[gy * WW + gx];
    size_t fb = (size_t)(b * 64 + w * 16) * HW + (size_t)gy * WW + gx;
#pragma unroll
    for (int i = 0; i < 16; ++i) {
      float f = fS[w * 1088 + i * 68 + l];
      feat[fb + (size_t)i * HW] = fmaxf(uu * f + f, 0.f);
    }
  }
  {
    unsigned short* ft = featT + (size_t)b * HW * 64;
    int c2 = (l & 7) * 2;
#pragma unroll
    for (int i = 0; i < 8; ++i) {
      int p = (l >> 3) + 8 * i;
      float f0 = fS[w * 1088 + c2 * 68 + p];
      float f1 = fS[w * 1088 + (c2 + 1) * 68 + p];
      int gy = y0 + (p >> 5), gx = x0 + (p & 31);
      float uu = ub[gy * WW + gx];
      f0 = fmaxf(uu * f0 + f0, 0.f);
      f1 = fmaxf(uu * f1 + f1, 0.f);
      unsigned v = (unsigned)f2bu(f0) | ((unsigned)f2bu(f1) << 16);
      *(unsigned*)&ft[((size_t)(gy * WW + gx)) * 64 + w * 16 + c2] = v;
    }
  }
}

// ------------------------------------------------------- bilinear sample ----
__global__ __launch_bounds__(256) void k_sample(const unsigned short* __restrict__ featT,
    const float* __restrict__ initp, const int* __restrict__ ct_ind,
    const int* __restrict__ ct_img, float* __restrict__ fp) {
  int n  = blockIdx.x;             // 0..127
  int ch = blockIdx.y;             // 0..1  (channel half)
  int t  = threadIdx.x;            // 0..255
  int w  = t >> 6, lane = t & 63;
  int c  = lane & 31;
  int ph = lane >> 5;

  __shared__ float sF[4128];       // [32c][129p]

  int img = ct_img[n];
  int ind = ct_ind[n];
  float ctx = (float)(ind % WW), cty = (float)(ind / WW);
  const unsigned short* fb = featT + (size_t)img * HW * 64 + ch * 32 + c;

  for (int i = 0; i < 17; ++i) {
    int p = i * 8 + w * 2 + ph;
    if (p < 129) {
      float px, py;
      if (p == 0) { px = ctx; py = cty; }
      else {
        px = initp[n * 256 + 2 * (p - 1)];
        py = initp[n * 256 + 2 * (p - 1) + 1];
      }
      float x = __fsub_rn(px, 0.5f), y = __fsub_rn(py, 0.5f);
      float x0f = floorf(x), y0f = floorf(y);
      float wx = __fsub_rn(x, x0f), wy = __fsub_rn(y, y0f);
      int x0 = (int)x0f, y0 = (int)y0f;
      float g[4];
#pragma unroll
      for (int qq = 0; qq < 4; ++qq) {
        int xi = x0 + (qq & 1), yi = y0 + (qq >> 1);
        bool valid = (xi >= 0) && (xi < WW) && (yi >= 0) && (yi < HH);
        int xc = min(max(xi, 0), WW - 1), yc = min(max(yi, 0), HH - 1);
        float v = bu2f(fb[(size_t)(yc * WW + xc) * 64]);
        g[qq] = valid ? v : 0.f;
      }
      float omx = __fsub_rn(1.f, wx), omy = __fsub_rn(1.f, wy);
      float r = __fadd_rn(__fadd_rn(__fadd_rn(
          __fmul_rn(__fmul_rn(g[0], omx), omy),
          __fmul_rn(__fmul_rn(g[1], wx),  omy)),
          __fmul_rn(__fmul_rn(g[2], omx), wy)),
          __fmul_rn(__fmul_rn(g[3], wx),  wy));
      sF[c * 129 + p] = r;
    }
  }
  __syncthreads();
  float* dst = fp + (size_t)n * 8256 + (size_t)ch * 4128;
  for (int idx = t; idx < 4128; idx += 256) dst[idx] = sF[idx];
}

// ------------------------------------------------- GEMM1: tmp = fp @ Wp^T ----
// v2: LDS pad 65->68 so the inner loop reads float4 (ds_read_b128; A-read
// broadcasts across tj-groups, B across tn-groups -> conflict-free), float4
// staging loads. Same FMA ordering -> bit-identical results.
__global__ __launch_bounds__(256) void k_gemm1(const float* __restrict__ fp,
    const float* __restrict__ wpoly, float* __restrict__ tmp) {
  int ntile = blockIdx.x;   // 0..1
  int jtile = blockIdx.y;   // 0..7
  int ks    = blockIdx.z;   // 0..31
  int c0 = (129 * ks) / 32, c1 = (129 * (ks + 1)) / 32;
  int t = threadIdx.x;
  int tn = t & 15, tj = t >> 4;
  __shared__ __align__(16) float aS[64][68];
  __shared__ __align__(16) float bS[64][68];
  float acc[4][4];
#pragma unroll
  for (int i = 0; i < 4; ++i)
#pragma unroll
    for (int j = 0; j < 4; ++j) acc[i][j] = 0.f;
  for (int ch = c0; ch < c1; ++ch) {
    int k0 = ch * 64;
    __syncthreads();
    for (int idx = t; idx < 1024; idx += 256) {
      int r = idx >> 4, c4 = (idx & 15) * 4;
      float4v va = *(const float4v*)&fp[(size_t)(ntile * 64 + r) * 8256 + k0 + c4];
      float4v vb = *(const float4v*)&wpoly[(size_t)(jtile * 64 + r) * 8256 + k0 + c4];
#pragma unroll
      for (int d = 0; d < 4; ++d) { aS[c4 + d][r] = va[d]; bS[c4 + d][r] = vb[d]; }
    }
    __syncthreads();
    for (int kk = 0; kk < 64; ++kk) {
      float4v a = *(const float4v*)&aS[kk][tn * 4];
      float4v bq = *(const float4v*)&bS[kk][tj * 4];
      acc[0][0] = fmaf(a[0], bq[0], acc[0][0]); acc[0][1] = fmaf(a[0], bq[1], acc[0][1]);
      acc[0][2] = fmaf(a[0], bq[2], acc[0][2]); acc[0][3] = fmaf(a[0], bq[3], acc[0][3]);
      acc[1][0] = fmaf(a[1], bq[0], acc[1][0]); acc[1][1] = fmaf(a[1], bq[1], acc[1][1]);
      acc[1][2] = fmaf(a[1], bq[2], acc[1][2]); acc[1][3] = fmaf(a[1], bq[3], acc[1][3]);
      acc[2][0] = fmaf(a[2], bq[0], acc[2][0]); acc[2][1] = fmaf(a[2], bq[1], acc[2][1]);
      acc[2][2] = fmaf(a[2], bq[2], acc[2][2]); acc[2][3] = fmaf(a[2], bq[3], acc[2][3]);
      acc[3][0] = fmaf(a[3], bq[0], acc[3][0]); acc[3][1] = fmaf(a[3], bq[1], acc[3][1]);
      acc[3][2] = fmaf(a[3], bq[2], acc[3][2]); acc[3][3] = fmaf(a[3], bq[3], acc[3][3]);
    }
  }
#pragma unroll
  for (int i = 0; i < 4; ++i)
#pragma unroll
    for (int j = 0; j < 4; ++j)
      atomicAdd(&tmp[(size_t)(ntile * 64 + tn * 4 + i) * 512 + jtile * 64 + tj * 4 + j], acc[i][j]);
}

// -------------------------------------- GEMM2 + coarse assembly + out1 ----
__global__ __launch_bounds__(256) void k_gemm2(const float* __restrict__ tmp,
    const float* __restrict__ wfT, const float* __restrict__ bfuse,
    const float* __restrict__ initp, float* __restrict__ coarse, float* __restrict__ out1) {
  int n = blockIdx.x, r = threadIdx.x;
  __shared__ float tS[512];
  tS[r] = tmp[n * 512 + r];
  tS[r + 256] = tmp[n * 512 + 256 + r];
  __syncthreads();
  float acc = 0.f;
  for (int j = 0; j < 512; ++j) acc = fmaf(wfT[j * 256 + r], tS[j], acc);
  acc = __fadd_rn(acc, bfuse[r]);
  float cr = __fadd_rn(__fmul_rn(acc, 4.0f), initp[n * 256 + r]);
  coarse[n * 256 + r] = cr;
  out1[n * 256 + r] = __fmul_rn(cr, 4.0f);
}

extern "C" void kernel_launch(void* const* d_in, const int* in_sizes, int n_in,
                              void* d_out, int out_size, void* d_ws, size_t ws_size,
                              hipStream_t stream) {
  const float* wh    = (const float*)d_in[0];
  const float* cnnf  = (const float*)d_in[1];
  const float* c1w   = (const float*)d_in[2];
  const float* c1b   = (const float*)d_in[3];
  const float* c2w   = (const float*)d_in[4];
  const float* c2b   = (const float*)d_in[5];
  const float* wpoly = (const float*)d_in[6];
  const float* wfuse = (const float*)d_in[7];
  const float* bfuse = (const float*)d_in[8];
  const int* ct_ind  = (const int*)d_in[9];
  const int* ct_img  = (const int*)d_in[10];

  float* ws    = (float*)d_ws;
  float* wfT   = ws;               // 131072 fp32
  float* initp = wfT + 131072;     // 32768
  float* coarse= initp + 32768;    // 32768
  float* tmp   = coarse + 32768;   // 65536
  float* u0    = tmp + 65536;      // 147456
  float* fpbuf = u0 + 147456;      // 1056768
  unsigned short* wB1 = (unsigned short*)(fpbuf + 1056768);  // 147456 bf16
  unsigned short* wB2 = wB1 + 147456;                        // 16384 bf16

  float* out0 = (float*)d_out;         // init_polys*4   32768
  float* out1 = out0 + 32768;          // coarse*4       32768
  float* out2 = out1 + 32768;          // mb_init        4718592
  float* out3 = out2 + 4718592;        // mb_c           4718592
  float* out4 = out3 + 4718592;        // feat           9437184
  float* feat = out4;                  // feat lives in out4 (fp32)
  // featT (bf16 channel-last shadow of gated feat) borrows out3's storage:
  // k_sample reads it, then the second k_pnp overwrites out3 with mb_c.
  unsigned short* featT = (unsigned short*)out3;

  k_prep<<<1408, 256, 0, stream>>>(c1w, c2w, wfuse, wB1, wB2, wfT, tmp);
  k_init_polys<<<128, 128, 0, stream>>>(wh, ct_ind, ct_img, initp, out0);
  k_pnp<<<dim3(192, 4), 256, 0, stream>>>(initp, out2, u0, nullptr);
  k_conv<<<2304, 256, 0, stream>>>(cnnf, wB1, c1b, wB2, c2b, u0, feat, featT);
  k_sample<<<dim3(128, 2), 256, 0, stream>>>(featT, initp, ct_ind, ct_img, fpbuf);
  k_gemm1<<<dim3(2, 8, 32), 256, 0, stream>>>(fpbuf, wpoly, tmp);
  k_gemm2<<<128, 256, 0, stream>>>(tmp, wfT, bfuse, initp, coarse, out1);
  k_pnp<<<dim3(192, 4), 256, 0, stream>>>(coarse, out3, nullptr, feat);
}

// Round 6
// 413.025 us; speedup vs baseline: 1.0468x; 1.0468x over previous
//
#include <hip/hip_runtime.h>
#include <hip/hip_bf16.h>

#define HH 192
#define WW 192
#define HW 36864           // 192*192
#define CHW 2359296        // 64*36864

typedef __attribute__((ext_vector_type(8))) short short8;
typedef __attribute__((ext_vector_type(4))) float float4v;
typedef __attribute__((ext_vector_type(4))) unsigned short ushort4v;

static __device__ __forceinline__ unsigned short f2bu(float f) {
  union { float f; unsigned u; } v; v.f = f;
  unsigned r = (v.u + 0x7fffu + ((v.u >> 16) & 1u)) >> 16;   // RNE bf16
  return (unsigned short)r;
}

static __device__ __forceinline__ float bu2f(unsigned short s) {
  union { unsigned u; float f; } v; v.u = ((unsigned)s) << 16;
  return v.f;
}

// ---------------------------------------------------------------- prep ----
// wB1/wB2 repack + wfuse transpose (blocks 0..1151) and init_polys+out0
// (blocks 1152..1279). tmp zeroing removed (gemm1 now writes partials).
__global__ void k_prep(const float* __restrict__ c1w, const float* __restrict__ c2w,
                       const float* __restrict__ wfuse,
                       unsigned short* __restrict__ wB1, unsigned short* __restrict__ wB2,
                       float* __restrict__ wfT,
                       const float* __restrict__ wh, const int* __restrict__ ct_ind,
                       const int* __restrict__ ct_img,
                       float* __restrict__ initp, float* __restrict__ out0) {
  int blk = blockIdx.x;
  if (blk >= 1152) {                 // fused k_init_polys
    int n = blk - 1152;              // 0..127
    int p = threadIdx.x;
    if (p < 128) {
      int ind = ct_ind[n], img = ct_img[n];
      int cx = ind % WW, cy = ind / WW;
      size_t base = ((size_t)(img * 256 + 2 * p)) * HW + (size_t)cy * WW + cx;
      float ox = wh[base];
      float oy = wh[base + HW];
      float px = __fadd_rn(__fmul_rn(ox, 10.0f), (float)cx);
      float py = __fadd_rn(__fmul_rn(oy, 10.0f), (float)cy);
      initp[n * 256 + 2 * p]     = px;
      initp[n * 256 + 2 * p + 1] = py;
      out0[n * 256 + 2 * p]      = __fmul_rn(px, 4.0f);
      out0[n * 256 + 2 * p + 1]  = __fmul_rn(py, 4.0f);
    }
    return;
  }
  int i = blk * 256 + threadIdx.x;
  if (i < 147456) {
    int T = i / 9216, r = i % 9216;
    int s = r / 512, e = r % 512;
    int l = e >> 3, j = e & 7;
    int m = l & 15, q = l >> 4;
    int oc = T * 16 + m;
    int k = s * 32 + q * 8 + j;
    int tap = k >> 6, ic = k & 63;
    int ky = tap / 3, kx = tap % 3;
    wB1[i] = f2bu(c1w[((oc * 64 + ic) * 3 + ky) * 3 + kx]);
    return;
  }
  int j2 = i - 147456;
  if (j2 < 16384) {
    int g = j2 / 512, e = j2 % 512;
    int l = e >> 3, jj = e & 7;
    int m = l & 15, q = l >> 4;
    int w = g / 8, s2 = g % 8;
    wB2[j2] = f2bu(c2w[(w * 16 + m) * 256 + s2 * 32 + q * 8 + jj]);
    return;
  }
  int k3 = j2 - 16384;
  if (k3 < 131072) { int jj = k3 >> 8, r = k3 & 255; wfT[k3] = wfuse[r * 512 + jj]; }
}

// ------------------------------------------------------ point-in-polygon ----
// block = (row, batch); 32 polys (batch 0: 0..31, else 32..63 — replicates
// reference _mask_batch slicing bug). Masks staged in LDS, union direct-
// stored. If fgate != null: reconstruct fp32 feat row from bf16 featT (fsrc),
// apply union gate, write out4 (fused k_final; featT lives in ws — no race).
__global__ __launch_bounds__(256) void k_pnp(const float* __restrict__ polys,
    float* __restrict__ outm, float* __restrict__ uout,
    float* __restrict__ fgate, const unsigned short* __restrict__ fsrc) {
  int row = blockIdx.x;       // 0..191
  int b   = blockIdx.y;       // 0..3
  int t = threadIdx.x;
  int w = t >> 6, lane = t & 63;
  __shared__ __align__(16) char smem[40960];   // xint 16KB | mrow 24.576KB
  float (*xint)[128] = (float (*)[128])smem;
  float (*mrow)[192] = (float (*)[192])(smem + 16384);
  unsigned short* frow = (unsigned short*)smem;   // 24576B, aliased (phase 4)
  __shared__ int   cnt[32];
  __shared__ float urow[192];
  if (t < 32) cnt[t] = 0;
  __syncthreads();
  int nbase = (b == 0) ? 0 : 32;
  float yy = (float)row;
  // phase 1: crossings
  for (int pc = 0; pc < 8; ++pc) {
    int c = w * 8 + pc;
    const float* P = polys + (nbase + c) * 256;
    for (int e = lane; e < 128; e += 64) {
      float y1 = P[2 * e + 1], y2 = P[2 * ((e + 1) & 127) + 1];
      if ((y1 > yy) != (y2 > yy)) {
        float x1 = P[2 * e], x2 = P[2 * ((e + 1) & 127)];
        float den = __fsub_rn(y2, y1);
        if (fabsf(den) < 1e-9f) den = 1e-9f;
        float xi = __fadd_rn(x1, __fdiv_rn(__fmul_rn(__fsub_rn(x2, x1), __fsub_rn(yy, y1)), den));
        xint[c][atomicAdd(&cnt[c], 1)] = xi;
      }
    }
  }
  __syncthreads();
  // phase 2: masks -> outm + LDS
  for (int idx = t; idx < 32 * 192; idx += 256) {
    int c = idx / 192, xp = idx - c * 192;
    float xf = (float)xp;
    int mm = cnt[c], cr = 0;
    for (int j = 0; j < mm; ++j) cr += (xf < xint[c][j]) ? 1 : 0;
    float mv = (float)(cr & 1);
    mrow[c][xp] = mv;
    outm[((size_t)(b * 32 + c) * HH + row) * WW + xp] = mv;
  }
  __syncthreads();
  // phase 3: union over polys
  if (t < 192) {
    float u = 0.f;
#pragma unroll
    for (int c = 0; c < 32; ++c) u = fmaxf(u, mrow[c][t]);
    urow[t] = u;
    if (uout) uout[(size_t)b * HW + (size_t)row * WW + t] = u;
  }
  __syncthreads();
  // phase 4: fused final gate from bf16 featT -> fp32 out4
  if (fgate) {
    // stage featT row slice (192 px x 64 ch) into LDS, coalesced
    const unsigned short* fr = fsrc + ((size_t)b * HW + (size_t)row * WW) * 64;
    for (int idx = t; idx < 3072; idx += 256)
      ((ushort4v*)frow)[idx] = ((const ushort4v*)fr)[idx];
    __syncthreads();
    float* fb = fgate + (size_t)b * CHW + (size_t)row * WW;
    for (int idx = t; idx < 3072; idx += 256) {
      int chn = idx / 48, qx = idx - chn * 48;
      float4v o;
#pragma unroll
      for (int j = 0; j < 4; ++j) {
        int xp = qx * 4 + j;
        float f = bu2f(frow[xp * 64 + chn]);
        float uu = urow[xp];
        o[j] = fmaxf(__fadd_rn(__fmul_rn(uu, f), f), 0.f);
      }
      *(float4v*)&fb[(size_t)chn * HW + qx * 4] = o;
    }
  }
}

// ------------------------------------------- fused conv1+relu+conv2+gate ----
// v5: fp32 feat store removed — featT (bf16 channel-last, in ws) is the only
// output; pnp2 reconstructs fp32 out4. Tile M=64 px, N=256 oc, 4 waves,
// 3 blocks/CU (reg budget 164/170 — do NOT add prefetch regs, round-3 lesson).
__global__ __launch_bounds__(256, 3) void k_conv(const float* __restrict__ x,
    const unsigned short* __restrict__ wB1, const float* __restrict__ b1,
    const unsigned short* __restrict__ wB2, const float* __restrict__ b2,
    const float* __restrict__ u0, unsigned short* __restrict__ featT) {
  int blk = blockIdx.x;            // 4 * 96 * 6 = 2304
  int b    = blk / 576;
  int rem  = blk % 576;
  int pair = rem / 6;
  int xs   = rem % 6;
  int y0 = pair * 2, x0 = xs * 32;
  int t = threadIdx.x;
  int w = t >> 6, l = t & 63;
  int m = l & 15, q = l >> 4;

  __shared__ __align__(16) unsigned short sb[16896];   // 33.8 KB union buffer

  // ---- stage x halo: 4 rows x 34 px x 64 ic -> bf16 [(r*34+xx)*72 + ic]
  {
    int kq = t & 7;
    int pr = t >> 3;
    for (int itr = 0; itr < 8; ++itr) {
      int pi = itr * 32 + pr;
      int r  = pi >> 6;
      int ic = pi & 63;
      int gy = y0 + r - 1;
      float4v v = (float4v){0.f, 0.f, 0.f, 0.f};
      if (gy >= 0 && gy < HH)
        v = *(const float4v*)&x[(size_t)(b * 64 + ic) * HW + (size_t)gy * WW + x0 + kq * 4];
      int base = (r * 34 + 1 + kq * 4) * 72 + ic;
      sb[base]       = f2bu(v[0]);
      sb[base + 72]  = f2bu(v[1]);
      sb[base + 144] = f2bu(v[2]);
      sb[base + 216] = f2bu(v[3]);
    }
    for (int itr = 0; itr < 2; ++itr) {
      int e = itr * 256 + t;
      int xxh = e >> 8;
      int rm = e & 255;
      int r = rm >> 6, ic = rm & 63;
      int gy = y0 + r - 1;
      int gx = x0 - 1 + xxh * 33;
      float v = 0.f;
      if (gy >= 0 && gy < HH && gx >= 0 && gx < WW)
        v = x[(size_t)(b * 64 + ic) * HW + (size_t)gy * WW + gx];
      sb[(r * 34 + xxh * 33) * 72 + ic] = f2bu(v);
    }
  }
  __syncthreads();

  // ---- conv1: M=64, N=64 (this wave), K=576
  float4v acc1[4][4];
#pragma unroll
  for (int nt = 0; nt < 4; ++nt) {
    float bv = b1[w * 64 + nt * 16 + m];
#pragma unroll
    for (int mt = 0; mt < 4; ++mt) acc1[mt][nt] = (float4v){bv, bv, bv, bv};
  }

#pragma unroll
  for (int s = 0; s < 18; ++s) {
    int tap = s >> 1, ky = tap / 3, kx = tap - ky * 3;
    int ic0 = (s & 1) * 32 + q * 8;
    short8 bF[4];
#pragma unroll
    for (int nt = 0; nt < 4; ++nt)
      bF[nt] = *(const short8*)&wB1[(size_t)((((w * 4 + nt) * 18 + s) * 512) + l * 8)];
    short8 aF[4];
#pragma unroll
    for (int mt = 0; mt < 4; ++mt) {
      int col  = (mt & 1) * 16 + m + kx;
      int rowi = ky + (mt >> 1);
      aF[mt] = *(const short8*)&sb[(rowi * 34 + col) * 72 + ic0];
    }
#pragma unroll
    for (int nt = 0; nt < 4; ++nt)
#pragma unroll
      for (int mt = 0; mt < 4; ++mt)
        acc1[mt][nt] = __builtin_amdgcn_mfma_f32_16x16x32_bf16(aF[mt], bF[nt], acc1[mt][nt], 0, 0, 0);
  }
  __syncthreads();

  // ---- y1 (relu, bf16) -> LDS [p*264 + oc], p = 0..63
#pragma unroll
  for (int mt = 0; mt < 4; ++mt)
#pragma unroll
    for (int nt = 0; nt < 4; ++nt)
#pragma unroll
      for (int r = 0; r < 4; ++r) {
        int p = mt * 16 + q * 4 + r;
        int oc = w * 64 + nt * 16 + m;
        sb[p * 264 + oc] = f2bu(fmaxf(acc1[mt][nt][r], 0.f));
      }
  __syncthreads();

  // ---- conv2: M=64, N=16 (this wave), K=256
  float4v acc2[4];
  {
    float bv = b2[w * 16 + m];
#pragma unroll
    for (int mt = 0; mt < 4; ++mt) acc2[mt] = (float4v){bv, bv, bv, bv};
  }
#pragma unroll
  for (int s2 = 0; s2 < 8; ++s2) {
    short8 bF2 = *(const short8*)&wB2[(size_t)(((w * 8 + s2) * 512) + l * 8)];
#pragma unroll
    for (int mt = 0; mt < 4; ++mt) {
      short8 a2 = *(const short8*)&sb[(mt * 16 + m) * 264 + s2 * 32 + q * 8];
      acc2[mt] = __builtin_amdgcn_mfma_f32_16x16x32_bf16(a2, bF2, acc2[mt], 0, 0, 0);
    }
  }
  __syncthreads();

  // ---- epilogue: transpose via LDS (wave-private, 16c x 64px pad 68),
  // then gated bf16 channel-last store only.
  float* fS = (float*)sb;
#pragma unroll
  for (int mt = 0; mt < 4; ++mt)
#pragma unroll
    for (int r = 0; r < 4; ++r) {
      int p = mt * 16 + q * 4 + r;
      fS[w * 1088 + m * 68 + p] = acc2[mt][r];
    }
  const float* ub = u0 + b * HW;
  {
    unsigned short* ft = featT + (size_t)b * HW * 64;
    int c2 = (l & 7) * 2;
#pragma unroll
    for (int i = 0; i < 8; ++i) {
      int p = (l >> 3) + 8 * i;
      float f0 = fS[w * 1088 + c2 * 68 + p];
      float f1 = fS[w * 1088 + (c2 + 1) * 68 + p];
      int gy = y0 + (p >> 5), gx = x0 + (p & 31);
      float uu = ub[gy * WW + gx];
      f0 = fmaxf(uu * f0 + f0, 0.f);
      f1 = fmaxf(uu * f1 + f1, 0.f);
      unsigned v = (unsigned)f2bu(f0) | ((unsigned)f2bu(f1) << 16);
      *(unsigned*)&ft[((size_t)(gy * WW + gx)) * 64 + w * 16 + c2] = v;
    }
  }
}

// ------------------------------------------------------- bilinear sample ----
__global__ __launch_bounds__(256) void k_sample(const unsigned short* __restrict__ featT,
    const float* __restrict__ initp, const int* __restrict__ ct_ind,
    const int* __restrict__ ct_img, float* __restrict__ fp) {
  int n  = blockIdx.x;             // 0..127
  int ch = blockIdx.y;             // 0..1  (channel half)
  int t  = threadIdx.x;            // 0..255
  int w  = t >> 6, lane = t & 63;
  int c  = lane & 31;
  int ph = lane >> 5;

  __shared__ float sF[4128];       // [32c][129p]

  int img = ct_img[n];
  int ind = ct_ind[n];
  float ctx = (float)(ind % WW), cty = (float)(ind / WW);
  const unsigned short* fb = featT + (size_t)img * HW * 64 + ch * 32 + c;

  for (int i = 0; i < 17; ++i) {
    int p = i * 8 + w * 2 + ph;
    if (p < 129) {
      float px, py;
      if (p == 0) { px = ctx; py = cty; }
      else {
        px = initp[n * 256 + 2 * (p - 1)];
        py = initp[n * 256 + 2 * (p - 1) + 1];
      }
      float x = __fsub_rn(px, 0.5f), y = __fsub_rn(py, 0.5f);
      float x0f = floorf(x), y0f = floorf(y);
      float wx = __fsub_rn(x, x0f), wy = __fsub_rn(y, y0f);
      int x0 = (int)x0f, y0 = (int)y0f;
      float g[4];
#pragma unroll
      for (int qq = 0; qq < 4; ++qq) {
        int xi = x0 + (qq & 1), yi = y0 + (qq >> 1);
        bool valid = (xi >= 0) && (xi < WW) && (yi >= 0) && (yi < HH);
        int xc = min(max(xi, 0), WW - 1), yc = min(max(yi, 0), HH - 1);
        float v = bu2f(fb[(size_t)(yc * WW + xc) * 64]);
        g[qq] = valid ? v : 0.f;
      }
      float omx = __fsub_rn(1.f, wx), omy = __fsub_rn(1.f, wy);
      float r = __fadd_rn(__fadd_rn(__fadd_rn(
          __fmul_rn(__fmul_rn(g[0], omx), omy),
          __fmul_rn(__fmul_rn(g[1], wx),  omy)),
          __fmul_rn(__fmul_rn(g[2], omx), wy)),
          __fmul_rn(__fmul_rn(g[3], wx),  wy));
      sF[c * 129 + p] = r;
    }
  }
  __syncthreads();
  float* dst = fp + (size_t)n * 8256 + (size_t)ch * 4128;
  for (int idx = t; idx < 4128; idx += 256) dst[idx] = sF[idx];
}

// ------------------------------------------------- GEMM1: part = fp @ Wp^T ----
// v3: no atomics — each (ntile,jtile,ks) block owns its 64x64 tile of
// part[ks] (32 x 128 x 512 fp32 partials); gemm2 reduces over ks.
__global__ __launch_bounds__(256) void k_gemm1(const float* __restrict__ fp,
    const float* __restrict__ wpoly, float* __restrict__ part) {
  int ntile = blockIdx.x;   // 0..1
  int jtile = blockIdx.y;   // 0..7
  int ks    = blockIdx.z;   // 0..31
  int c0 = (129 * ks) / 32, c1 = (129 * (ks + 1)) / 32;
  int t = threadIdx.x;
  int tn = t & 15, tj = t >> 4;
  __shared__ __align__(16) float aS[64][68];
  __shared__ __align__(16) float bS[64][68];
  float acc[4][4];
#pragma unroll
  for (int i = 0; i < 4; ++i)
#pragma unroll
    for (int j = 0; j < 4; ++j) acc[i][j] = 0.f;
  for (int ch = c0; ch < c1; ++ch) {
    int k0 = ch * 64;
    __syncthreads();
    for (int idx = t; idx < 1024; idx += 256) {
      int r = idx >> 4, c4 = (idx & 15) * 4;
      float4v va = *(const float4v*)&fp[(size_t)(ntile * 64 + r) * 8256 + k0 + c4];
      float4v vb = *(const float4v*)&wpoly[(size_t)(jtile * 64 + r) * 8256 + k0 + c4];
#pragma unroll
      for (int d = 0; d < 4; ++d) { aS[c4 + d][r] = va[d]; bS[c4 + d][r] = vb[d]; }
    }
    __syncthreads();
    for (int kk = 0; kk < 64; ++kk) {
      float4v a = *(const float4v*)&aS[kk][tn * 4];
      float4v bq = *(const float4v*)&bS[kk][tj * 4];
      acc[0][0] = fmaf(a[0], bq[0], acc[0][0]); acc[0][1] = fmaf(a[0], bq[1], acc[0][1]);
      acc[0][2] = fmaf(a[0], bq[2], acc[0][2]); acc[0][3] = fmaf(a[0], bq[3], acc[0][3]);
      acc[1][0] = fmaf(a[1], bq[0], acc[1][0]); acc[1][1] = fmaf(a[1], bq[1], acc[1][1]);
      acc[1][2] = fmaf(a[1], bq[2], acc[1][2]); acc[1][3] = fmaf(a[1], bq[3], acc[1][3]);
      acc[2][0] = fmaf(a[2], bq[0], acc[2][0]); acc[2][1] = fmaf(a[2], bq[1], acc[2][1]);
      acc[2][2] = fmaf(a[2], bq[2], acc[2][2]); acc[2][3] = fmaf(a[2], bq[3], acc[2][3]);
      acc[3][0] = fmaf(a[3], bq[0], acc[3][0]); acc[3][1] = fmaf(a[3], bq[1], acc[3][1]);
      acc[3][2] = fmaf(a[3], bq[2], acc[3][2]); acc[3][3] = fmaf(a[3], bq[3], acc[3][3]);
    }
  }
  float* dst = part + (size_t)ks * 65536;
#pragma unroll
  for (int i = 0; i < 4; ++i) {
    float4v o = (float4v){acc[i][0], acc[i][1], acc[i][2], acc[i][3]};
    *(float4v*)&dst[(size_t)(ntile * 64 + tn * 4 + i) * 512 + jtile * 64 + tj * 4] = o;
  }
}

// -------------------- GEMM2 (+ ks-reduce) + coarse assembly + out1 ----
__global__ __launch_bounds__(256) void k_gemm2(const float* __restrict__ part,
    const float* __restrict__ wfT, const float* __restrict__ bfuse,
    const float* __restrict__ initp, float* __restrict__ coarse, float* __restrict__ out1) {
  int n = blockIdx.x, r = threadIdx.x;
  __shared__ float tS[512];
  float s0 = 0.f, s1 = 0.f;
  for (int ks = 0; ks < 32; ++ks) {
    const float* p = part + (size_t)ks * 65536 + (size_t)n * 512;
    s0 = __fadd_rn(s0, p[r]);
    s1 = __fadd_rn(s1, p[r + 256]);
  }
  tS[r] = s0;
  tS[r + 256] = s1;
  __syncthreads();
  float acc = 0.f;
  for (int j = 0; j < 512; ++j) acc = fmaf(wfT[j * 256 + r], tS[j], acc);
  acc = __fadd_rn(acc, bfuse[r]);
  float cr = __fadd_rn(__fmul_rn(acc, 4.0f), initp[n * 256 + r]);
  coarse[n * 256 + r] = cr;
  out1[n * 256 + r] = __fmul_rn(cr, 4.0f);
}

extern "C" void kernel_launch(void* const* d_in, const int* in_sizes, int n_in,
                              void* d_out, int out_size, void* d_ws, size_t ws_size,
                              hipStream_t stream) {
  const float* wh    = (const float*)d_in[0];
  const float* cnnf  = (const float*)d_in[1];
  const float* c1w   = (const float*)d_in[2];
  const float* c1b   = (const float*)d_in[3];
  const float* c2w   = (const float*)d_in[4];
  const float* c2b   = (const float*)d_in[5];
  const float* wpoly = (const float*)d_in[6];
  const float* wfuse = (const float*)d_in[7];
  const float* bfuse = (const float*)d_in[8];
  const int* ct_ind  = (const int*)d_in[9];
  const int* ct_img  = (const int*)d_in[10];

  float* ws    = (float*)d_ws;
  float* wfT   = ws;               // 131072 fp32
  float* initp = wfT + 131072;     // 32768
  float* coarse= initp + 32768;    // 32768
  float* u0    = coarse + 32768;   // 147456
  float* fpbuf = u0 + 147456;      // 1056768
  float* part  = fpbuf + 1056768;  // 32*128*512 = 2097152
  unsigned short* wB1 = (unsigned short*)(part + 2097152);   // 147456 bf16
  unsigned short* wB2 = wB1 + 147456;                        // 16384 bf16
  unsigned short* featT = wB2 + 16384;                       // 9437184 bf16 (18.9 MB)
  // total ~33.2 MB of ws

  float* out0 = (float*)d_out;         // init_polys*4   32768
  float* out1 = out0 + 32768;          // coarse*4       32768
  float* out2 = out1 + 32768;          // mb_init        4718592
  float* out3 = out2 + 4718592;        // mb_c           4718592
  float* out4 = out3 + 4718592;        // feat           9437184

  k_prep<<<1280, 256, 0, stream>>>(c1w, c2w, wfuse, wB1, wB2, wfT,
                                   wh, ct_ind, ct_img, initp, out0);
  k_pnp<<<dim3(192, 4), 256, 0, stream>>>(initp, out2, u0, nullptr, nullptr);
  k_conv<<<2304, 256, 0, stream>>>(cnnf, wB1, c1b, wB2, c2b, u0, featT);
  k_sample<<<dim3(128, 2), 256, 0, stream>>>(featT, initp, ct_ind, ct_img, fpbuf);
  k_gemm1<<<dim3(2, 8, 32), 256, 0, stream>>>(fpbuf, wpoly, part);
  k_gemm2<<<128, 256, 0, stream>>>(part, wfT, bfuse, initp, coarse, out1);
  k_pnp<<<dim3(192, 4), 256, 0, stream>>>(coarse, out3, nullptr, out4, featT);
}